// Round 2
// 1003.657 us; speedup vs baseline: 1.0257x; 1.0257x over previous
//
#include <hip/hip_runtime.h>
#include <cmath>

#define NMUL 32
#define IN_DIM 128
#define MSG_DIM 128

typedef float vfloat4 __attribute__((ext_vector_type(4)));

__global__ __launch_bounds__(256)
void tp_scatter_kernel(const float* __restrict__ x,
                       const float* __restrict__ edge_attr,
                       const float* __restrict__ edge_weight,
                       const int* __restrict__ edge_src,
                       const int* __restrict__ edge_dst,
                       float* __restrict__ out)
{
    const float INV_SQRT3 = 0.5773502691896258f;
    const float PATH_NORM = 0.125f;            // 1/sqrt(2*32)

    const int e   = blockIdx.x;
    const int tid = threadIdx.x;
    const int u   = tid >> 3;   // 0..31 : reduction index
    const int wq  = tid & 7;    // 0..7  : 4 output columns each (w = wq*4..wq*4+3)
    (void)wq;

    __shared__ float xrow[IN_DIM];             // [0..31]=x0, [32..127]=x1 (u-major, 3/u)
    __shared__ float red[256 * 17];            // stride 17 -> conflict-free

    // Issue the dominant 16KB weight load FIRST so its latency overlaps the
    // x-row staging + barrier. Non-temporal: streamed once, don't evict x/out.
    const vfloat4* W4 = (const vfloat4*)(edge_weight + (size_t)e * 4096);
    const vfloat4 w000 = __builtin_nontemporal_load(W4 + 0*256 + tid);
    const vfloat4 w011 = __builtin_nontemporal_load(W4 + 1*256 + tid);
    const vfloat4 w101 = __builtin_nontemporal_load(W4 + 2*256 + tid);
    const vfloat4 w110 = __builtin_nontemporal_load(W4 + 3*256 + tid);

    const int src = edge_src[e];
    const int dst = edge_dst[e];
    const float4 ea = ((const float4*)edge_attr)[e];
    const float e0  = ea.x;
    const float e1x = ea.y, e1y = ea.z, e1z = ea.w;

    // stage x[src] row with 32 float4 loads
    if (tid < 32) {
        ((float4*)xrow)[tid] = ((const float4*)(x + (size_t)src * IN_DIM))[tid];
    }
    __syncthreads();

    // per-thread scalars for its fixed u (su computed per-thread: no sS stage,
    // no extra barrier -- x10..x12 are needed for d0..d2 anyway)
    const float x0u = xrow[u];
    const float x10 = xrow[32 + u*3 + 0];
    const float x11 = xrow[32 + u*3 + 1];
    const float x12 = xrow[32 + u*3 + 2];
    const float su  = x10*e1x + x11*e1y + x12*e1z;

    const float c000 = e0 * x0u;              // feeds w000 into out0
    const float c110 = INV_SQRT3 * su;        // feeds w110 into out0
    const float b0 = x0u * e1x, b1 = x0u * e1y, b2 = x0u * e1z;  // w011 -> out1[:,k]
    const float d0 = x10 * e0,  d1 = x11 * e0,  d2 = x12 * e0;   // w101 -> out1[:,k]

    float* r = red + tid * 17;
    // slots 0..3  : out0 partial (4 cols)
    r[0]  = w000[0]*c000 + w110[0]*c110;
    r[1]  = w000[1]*c000 + w110[1]*c110;
    r[2]  = w000[2]*c000 + w110[2]*c110;
    r[3]  = w000[3]*c000 + w110[3]*c110;
    // slots 4+k*4+c : out1 partial for k, col c
    r[4]  = w011[0]*b0 + w101[0]*d0;
    r[5]  = w011[1]*b0 + w101[1]*d0;
    r[6]  = w011[2]*b0 + w101[2]*d0;
    r[7]  = w011[3]*b0 + w101[3]*d0;
    r[8]  = w011[0]*b1 + w101[0]*d1;
    r[9]  = w011[1]*b1 + w101[1]*d1;
    r[10] = w011[2]*b1 + w101[2]*d1;
    r[11] = w011[3]*b1 + w101[3]*d1;
    r[12] = w011[0]*b2 + w101[0]*d2;
    r[13] = w011[1]*b2 + w101[1]*d2;
    r[14] = w011[2]*b2 + w101[2]*d2;
    r[15] = w011[3]*b2 + w101[3]*d2;
    __syncthreads();

    // threads 0..127: one message element each; reduce over the 32 u-partials
    if (tid < MSG_DIM) {
        int wqo, slot;
        float scale;
        if (tid < 32) {
            wqo  = tid >> 2;
            slot = tid & 3;
            scale = PATH_NORM;
        } else {
            int j = tid - 32;       // out1 flat index = w*3 + k
            int w = j / 3;
            int k = j - 3 * w;
            wqo  = w >> 2;
            slot = 4 + k*4 + (w & 3);
            scale = PATH_NORM * INV_SQRT3;
        }
        float sacc = 0.0f;
        #pragma unroll
        for (int uu = 0; uu < 32; ++uu)
            sacc += red[(uu*8 + wqo) * 17 + slot];
        float v = sacc * scale;
        if (!isfinite(v)) v = 0.0f;   // nan_to_num(nan/±inf -> 0)
        atomicAdd(out + (size_t)dst * MSG_DIM + tid, v);
    }
}

extern "C" void kernel_launch(void* const* d_in, const int* in_sizes, int n_in,
                              void* d_out, int out_size, void* d_ws, size_t ws_size,
                              hipStream_t stream) {
    const float* x           = (const float*)d_in[0];
    const float* edge_attr   = (const float*)d_in[1];
    const float* edge_weight = (const float*)d_in[2];
    const int*   edge_src    = (const int*)d_in[3];
    const int*   edge_dst    = (const int*)d_in[4];
    float*       out         = (float*)d_out;

    const int E = in_sizes[3];

    // Zero ONLY the logical output: num_nodes*MSG_DIM == in_sizes[0] floats
    // (x has num_nodes*IN_DIM elements and IN_DIM == MSG_DIM). The harness's
    // out_size is a much larger arena -- zeroing all of it cost ~517us/launch.
    size_t zero_elems = (size_t)in_sizes[0];
    if ((size_t)out_size < zero_elems) zero_elems = (size_t)out_size;
    (void)hipMemsetAsync(d_out, 0, zero_elems * sizeof(float), stream);

    tp_scatter_kernel<<<E, 256, 0, stream>>>(x, edge_attr, edge_weight,
                                             edge_src, edge_dst, out);
}